// Round 6
// baseline (836.688 us; speedup 1.0000x reference)
//
#include <hip/hip_runtime.h>
#include <math.h>

#define BQ 4
#define LQ 1024
#define DM 256
#define DI 512
#define NS 16
#define DTR 16
#define KC 4
#define NL 8

typedef __bf16 bf16;
typedef __bf16 bf16x4 __attribute__((ext_vector_type(4)));
typedef __bf16 bf16x8 __attribute__((ext_vector_type(8)));
typedef float f32x4 __attribute__((ext_vector_type(4)));

static __device__ __forceinline__ float sigmoidf_(float x) { return 1.0f / (1.0f + expf(-x)); }
static __device__ __forceinline__ float siluf_(float x) { return x * sigmoidf_(x); }
static __device__ __forceinline__ float softplusf_(float x) {
    return fmaxf(x, 0.0f) + log1pf(expf(-fabsf(x)));
}
static __device__ __forceinline__ void cvt_hilo(float x, bf16& hi, bf16& lo) {
    hi = (bf16)x;
    lo = (bf16)(x - (float)hi);
}

// ---------------- embed
__global__ void k_embed(const float* __restrict__ x, const float* __restrict__ pos,
                        const float* __restrict__ We, const float* __restrict__ be,
                        float* __restrict__ h) {
    int idx = blockIdx.x * 256 + threadIdx.x;
    int d = idx % DM;
    int l = (idx / DM) % LQ;
    int b = idx / (DM * LQ);
    float v;
    if (d < 128) {
        float x0 = x[(b * LQ + l) * 2 + 0];
        float x1 = x[(b * LQ + l) * 2 + 1];
        v = fmaf(x0, We[d], fmaf(x1, We[128 + d], be[d]));
    } else {
        v = pos[l * 128 + (d - 128)];
    }
    h[idx] = v;
}

// ---------------- weight transpose + bf16 (RNE): W[lay][K][N] -> T[lay][N][K]
__global__ __launch_bounds__(256) void k_wt1(const float* __restrict__ W, bf16* __restrict__ T,
                                             int K, int N) {
    int k0 = blockIdx.x * 32, n0 = blockIdx.y * 32, lay = blockIdx.z;
    __shared__ float ts[32][36];
    int r = threadIdx.x >> 3, q = threadIdx.x & 7;
    float4 v = *(const float4*)(W + ((size_t)lay * K + k0 + r) * N + n0 + q * 4);
    *(float4*)&ts[r][q * 4] = v;
    __syncthreads();
    bf16x4 hv;
#pragma unroll
    for (int i = 0; i < 4; i++) hv[i] = (bf16)ts[q * 4 + i][r];
    size_t o = ((size_t)lay * N + n0 + r) * K + k0 + q * 4;
    *(bf16x4*)(T + o) = hv;
}

// ---------------- fused rmsnorm + GEMM1: xg = rmsnorm(h)*lnw @ W_in  (M=4096,N=1024,K=256)
// A built in-kernel (hi/lo bf16, LDS). Also zeroes sp (blockIdx.x==0).
__global__ __launch_bounds__(256) void k_ln_gemm(const float* __restrict__ h,
                                                 const float* __restrict__ lnw,
                                                 const bf16* __restrict__ Bw,
                                                 float* __restrict__ xg,
                                                 float* __restrict__ sp) {
    __shared__ __align__(16) bf16 sA[2][64 * 256];  // [plane hi/lo][row*256 + swz]
    __shared__ __align__(16) bf16 sB[2][64 * 64];   // double-buffered B
    const int tid = threadIdx.x;
    const int lane = tid & 63, wave = tid >> 6;
    const int wr = wave >> 1, wc = wave & 1;
    const int bm = blockIdx.y * 64, bn = blockIdx.x * 64;
    // ---- rmsnorm into sA
    const int qrow = tid >> 4, qcol = tid & 15;
    float wv[16];
    {
        const float4* wp = (const float4*)(lnw + qcol * 16);
#pragma unroll
        for (int i = 0; i < 4; i++) {
            float4 t = wp[i];
            wv[4 * i] = t.x; wv[4 * i + 1] = t.y; wv[4 * i + 2] = t.z; wv[4 * i + 3] = t.w;
        }
    }
#pragma unroll
    for (int rr = 0; rr < 4; ++rr) {
        int row = rr * 16 + qrow;
        const float4* hp = (const float4*)(h + (size_t)(bm + row) * DM + qcol * 16);
        float v[16];
        float ss = 0.f;
#pragma unroll
        for (int i = 0; i < 4; i++) {
            float4 t = hp[i];
            v[4 * i] = t.x; v[4 * i + 1] = t.y; v[4 * i + 2] = t.z; v[4 * i + 3] = t.w;
            ss += t.x * t.x + t.y * t.y + t.z * t.z + t.w * t.w;
        }
        ss += __shfl_xor(ss, 1);
        ss += __shfl_xor(ss, 2);
        ss += __shfl_xor(ss, 4);
        ss += __shfl_xor(ss, 8);
        float scale = 1.0f / sqrtf(ss * (1.0f / DM) + 1e-5f);
#pragma unroll
        for (int c2 = 0; c2 < 2; ++c2) {
            bf16x8 hv8, lv8;
#pragma unroll
            for (int j = 0; j < 8; ++j) {
                float o = v[c2 * 8 + j] * scale * wv[c2 * 8 + j];
                bf16 hb, lb;
                cvt_hilo(o, hb, lb);
                hv8[j] = hb; lv8[j] = lb;
            }
            int chunk = (2 * qcol + c2) ^ (row & 7);
            int off = row * 256 + chunk * 8;
            *(bf16x8*)&sA[0][off] = hv8;
            *(bf16x8*)&sA[1][off] = lv8;
        }
    }
    // ---- B staging
    const int srow = tid >> 2, sc0 = (tid & 3) * 2, ssw = srow & 7;
    const int ld0 = srow * 64 + (sc0 ^ ssw) * 8;
    const int ld1 = srow * 64 + ((sc0 + 1) ^ ssw) * 8;
    const size_t boff = (size_t)(bn + srow) * 256 + sc0 * 8;
    uint4 rB0 = *(const uint4*)(Bw + boff);
    uint4 rB1 = *(const uint4*)(Bw + boff + 8);
    *(uint4*)&sB[0][ld0] = rB0;
    *(uint4*)&sB[0][ld1] = rB1;
    __syncthreads();
    const int r15 = lane & 15, g = lane >> 4;
    const int arow0 = wr * 32 + r15;
    const int brow0 = wc * 32 + r15;
    const int asw = arow0 & 7, bsw = brow0 & 7;
    f32x4 acc[2][2] = {};
    int cur = 0;
#pragma unroll
    for (int t = 0; t < 4; ++t) {
        if (t < 3) {
            size_t ko = (size_t)(t + 1) * 64;
            rB0 = *(const uint4*)(Bw + boff + ko);
            rB1 = *(const uint4*)(Bw + boff + ko + 8);
        }
#pragma unroll
        for (int kk = 0; kk < 2; ++kk) {
            const int ca = ((t * 8 + kk * 4 + g) ^ asw) * 8;
            const int cb = ((kk * 4 + g) ^ bsw) * 8;
            bf16x8 a0h = *(const bf16x8*)&sA[0][arow0 * 256 + ca];
            bf16x8 a1h = *(const bf16x8*)&sA[0][(arow0 + 16) * 256 + ca];
            bf16x8 a0l = *(const bf16x8*)&sA[1][arow0 * 256 + ca];
            bf16x8 a1l = *(const bf16x8*)&sA[1][(arow0 + 16) * 256 + ca];
            bf16x8 b0 = *(const bf16x8*)&sB[cur][brow0 * 64 + cb];
            bf16x8 b1 = *(const bf16x8*)&sB[cur][(brow0 + 16) * 64 + cb];
            acc[0][0] = __builtin_amdgcn_mfma_f32_16x16x32_bf16(a0h, b0, acc[0][0], 0, 0, 0);
            acc[0][1] = __builtin_amdgcn_mfma_f32_16x16x32_bf16(a0h, b1, acc[0][1], 0, 0, 0);
            acc[1][0] = __builtin_amdgcn_mfma_f32_16x16x32_bf16(a1h, b0, acc[1][0], 0, 0, 0);
            acc[1][1] = __builtin_amdgcn_mfma_f32_16x16x32_bf16(a1h, b1, acc[1][1], 0, 0, 0);
            acc[0][0] = __builtin_amdgcn_mfma_f32_16x16x32_bf16(a0l, b0, acc[0][0], 0, 0, 0);
            acc[0][1] = __builtin_amdgcn_mfma_f32_16x16x32_bf16(a0l, b1, acc[0][1], 0, 0, 0);
            acc[1][0] = __builtin_amdgcn_mfma_f32_16x16x32_bf16(a1l, b0, acc[1][0], 0, 0, 0);
            acc[1][1] = __builtin_amdgcn_mfma_f32_16x16x32_bf16(a1l, b1, acc[1][1], 0, 0, 0);
        }
        if (t < 3) {
            int nb = cur ^ 1;
            *(uint4*)&sB[nb][ld0] = rB0;
            *(uint4*)&sB[nb][ld1] = rB1;
        }
        __syncthreads();
        cur ^= 1;
    }
#pragma unroll
    for (int i = 0; i < 2; i++)
#pragma unroll
        for (int j = 0; j < 2; j++) {
            int row0 = bm + wr * 32 + i * 16 + g * 4;
            int col = bn + wc * 32 + j * 16 + r15;
#pragma unroll
            for (int r = 0; r < 4; r++) {
                xg[(size_t)(row0 + r) * 1024 + col] = acc[i][j][r];
            }
        }
    if (blockIdx.x == 0) {
        float4 z = {0.f, 0.f, 0.f, 0.f};
        for (int f = tid; f < 768; f += 256) *(float4*)(sp + (size_t)bm * 48 + f * 4) = z;
    }
}

// ---------------- gemm2: h += y(hi/lo) @ WoT   (M=4096,N=256,K=512)
__global__ __launch_bounds__(256) void k_gemm2t(const bf16* __restrict__ Ah,
                                                const bf16* __restrict__ Al,
                                                const bf16* __restrict__ Bw,
                                                float* __restrict__ C, int M, int N, int K) {
    __shared__ __align__(16) bf16 sA[2][2][64 * 64];
    __shared__ __align__(16) bf16 sB[2][64 * 64];
    const int tid = threadIdx.x;
    const int lane = tid & 63, wave = tid >> 6;
    const int wr = wave >> 1, wc = wave & 1;
    const int bm = blockIdx.y * 64, bn = blockIdx.x * 64;
    const int srow = tid >> 2, sc0 = (tid & 3) * 2, ssw = srow & 7;
    const int ld0 = srow * 64 + (sc0 ^ ssw) * 8;
    const int ld1 = srow * 64 + ((sc0 + 1) ^ ssw) * 8;
    const size_t aoff = (size_t)(bm + srow) * K + sc0 * 8;
    const size_t boff = (size_t)(bn + srow) * K + sc0 * 8;
    const int r15 = lane & 15, g = lane >> 4;
    const int arow0 = wr * 32 + r15;
    const int brow0 = wc * 32 + r15;
    const int asw = arow0 & 7, bsw = brow0 & 7;
    f32x4 acc[2][2] = {};
    const int nt = K >> 6;
    uint4 rA0h = *(const uint4*)(Ah + aoff), rA1h = *(const uint4*)(Ah + aoff + 8);
    uint4 rA0l = *(const uint4*)(Al + aoff), rA1l = *(const uint4*)(Al + aoff + 8);
    uint4 rB0 = *(const uint4*)(Bw + boff), rB1 = *(const uint4*)(Bw + boff + 8);
    *(uint4*)&sA[0][0][ld0] = rA0h; *(uint4*)&sA[0][0][ld1] = rA1h;
    *(uint4*)&sA[0][1][ld0] = rA0l; *(uint4*)&sA[0][1][ld1] = rA1l;
    *(uint4*)&sB[0][ld0] = rB0;     *(uint4*)&sB[0][ld1] = rB1;
    __syncthreads();
    int cur = 0;
    for (int t = 0; t < nt; ++t) {
        if (t + 1 < nt) {
            size_t ko = (size_t)(t + 1) * 64;
            rA0h = *(const uint4*)(Ah + aoff + ko); rA1h = *(const uint4*)(Ah + aoff + ko + 8);
            rA0l = *(const uint4*)(Al + aoff + ko); rA1l = *(const uint4*)(Al + aoff + ko + 8);
            rB0 = *(const uint4*)(Bw + boff + ko);  rB1 = *(const uint4*)(Bw + boff + ko + 8);
        }
#pragma unroll
        for (int kk = 0; kk < 2; ++kk) {
            const int ca = ((kk * 4 + g) ^ asw) * 8;
            const int cb = ((kk * 4 + g) ^ bsw) * 8;
            bf16x8 a0h = *(const bf16x8*)&sA[cur][0][arow0 * 64 + ca];
            bf16x8 a1h = *(const bf16x8*)&sA[cur][0][(arow0 + 16) * 64 + ca];
            bf16x8 a0l = *(const bf16x8*)&sA[cur][1][arow0 * 64 + ca];
            bf16x8 a1l = *(const bf16x8*)&sA[cur][1][(arow0 + 16) * 64 + ca];
            bf16x8 b0 = *(const bf16x8*)&sB[cur][brow0 * 64 + cb];
            bf16x8 b1 = *(const bf16x8*)&sB[cur][(brow0 + 16) * 64 + cb];
            acc[0][0] = __builtin_amdgcn_mfma_f32_16x16x32_bf16(a0h, b0, acc[0][0], 0, 0, 0);
            acc[0][1] = __builtin_amdgcn_mfma_f32_16x16x32_bf16(a0h, b1, acc[0][1], 0, 0, 0);
            acc[1][0] = __builtin_amdgcn_mfma_f32_16x16x32_bf16(a1h, b0, acc[1][0], 0, 0, 0);
            acc[1][1] = __builtin_amdgcn_mfma_f32_16x16x32_bf16(a1h, b1, acc[1][1], 0, 0, 0);
            acc[0][0] = __builtin_amdgcn_mfma_f32_16x16x32_bf16(a0l, b0, acc[0][0], 0, 0, 0);
            acc[0][1] = __builtin_amdgcn_mfma_f32_16x16x32_bf16(a0l, b1, acc[0][1], 0, 0, 0);
            acc[1][0] = __builtin_amdgcn_mfma_f32_16x16x32_bf16(a1l, b0, acc[1][0], 0, 0, 0);
            acc[1][1] = __builtin_amdgcn_mfma_f32_16x16x32_bf16(a1l, b1, acc[1][1], 0, 0, 0);
        }
        if (t + 1 < nt) {
            int nb = cur ^ 1;
            *(uint4*)&sA[nb][0][ld0] = rA0h; *(uint4*)&sA[nb][0][ld1] = rA1h;
            *(uint4*)&sA[nb][1][ld0] = rA0l; *(uint4*)&sA[nb][1][ld1] = rA1l;
            *(uint4*)&sB[nb][ld0] = rB0;     *(uint4*)&sB[nb][ld1] = rB1;
        }
        __syncthreads();
        cur ^= 1;
    }
#pragma unroll
    for (int i = 0; i < 2; i++)
#pragma unroll
        for (int j = 0; j < 2; j++) {
            int row0 = bm + wr * 32 + i * 16 + g * 4;
            int col = bn + wc * 32 + j * 16 + r15;
#pragma unroll
            for (int r = 0; r < 4; r++) {
                size_t o = (size_t)(row0 + r) * N + col;
                C[o] = acc[i][j][r] + C[o];
            }
        }
}

// ---------------- causal depthwise conv (K=4) + SiLU + fused sp split-K partials
__global__ __launch_bounds__(256) void k_conv_sp(const float* __restrict__ xg,
                                                 const float* __restrict__ cw,
                                                 const float* __restrict__ cb,
                                                 const float* __restrict__ Wx,
                                                 float* __restrict__ hs,
                                                 float* __restrict__ sp) {
    int l0 = blockIdx.x * 32, d0 = blockIdx.y * 64, b = blockIdx.z;
    __shared__ float xs[35][68];
    __shared__ float cs[32][68];
    __shared__ float wxs[64][48];
    int tid = threadIdx.x;
    for (int idx = tid; idx < 35 * 16; idx += 256) {
        int r = idx >> 4, q = idx & 15;
        int l = l0 - 3 + r;
        float4 v = {0.f, 0.f, 0.f, 0.f};
        if (l >= 0) v = *(const float4*)(xg + ((size_t)(b * LQ + l)) * 1024 + d0 + q * 4);
        *(float4*)&xs[r][q * 4] = v;
    }
    for (int idx = tid; idx < 64 * 12; idx += 256) {
        int r = idx / 12, q = idx % 12;
        *(float4*)&wxs[r][q * 4] = *(const float4*)(Wx + (size_t)(d0 + r) * 48 + q * 4);
    }
    __syncthreads();
    int dl = tid >> 2, lq = tid & 3;
    const float* w = cw + (d0 + dl) * KC;
    float w0 = w[0], w1 = w[1], w2 = w[2], w3 = w[3];
    float bb = cb[d0 + dl];
    float out[8];
    float x0 = xs[lq * 8 + 0][dl];
    float x1 = xs[lq * 8 + 1][dl];
    float x2 = xs[lq * 8 + 2][dl];
#pragma unroll
    for (int j = 0; j < 8; ++j) {
        float x3 = xs[lq * 8 + 3 + j][dl];
        float v = fmaf(w0, x0, fmaf(w1, x1, fmaf(w2, x2, fmaf(w3, x3, bb))));
        out[j] = siluf_(v);
        x0 = x1; x1 = x2; x2 = x3;
    }
#pragma unroll
    for (int j = 0; j < 8; ++j) cs[lq * 8 + j][dl] = out[j];
    __syncthreads();
    for (int idx = tid; idx < 32 * 16; idx += 256) {
        int r = idx >> 4, q = idx & 15;
        *(float4*)(hs + ((size_t)(b * LQ + l0 + r)) * DI + d0 + q * 4) =
            *(const float4*)&cs[r][q * 4];
    }
    for (int o = tid; o < 32 * 48; o += 256) {
        int l = o / 48, j = o % 48;
        float acc = 0.f;
#pragma unroll
        for (int dq = 0; dq < 16; ++dq) {
            float4 cv = *(const float4*)&cs[l][dq * 4];
            acc = fmaf(cv.x, wxs[dq * 4 + 0][j], acc);
            acc = fmaf(cv.y, wxs[dq * 4 + 1][j], acc);
            acc = fmaf(cv.z, wxs[dq * 4 + 2][j], acc);
            acc = fmaf(cv.w, wxs[dq * 4 + 3][j], acc);
        }
        atomicAdd(&sp[((size_t)(b * LQ) + l0 + l) * 48 + j], acc);
    }
}

// ---------------- scan phase A
__global__ __launch_bounds__(256) void k_scanA(const float* __restrict__ hs,
                                               const float* __restrict__ sp,
                                               const float* __restrict__ Wdt,
                                               const float* __restrict__ bdt,
                                               const float* __restrict__ Alog,
                                               float* __restrict__ PS) {
    int c = blockIdx.x, b = blockIdx.z;
    int t = threadIdx.x;
    int d = blockIdx.y * 256 + t;
    __shared__ float sps[32][48];
    for (int o = t; o < 32 * 12; o += 256) {
        int l = o / 12, q = o % 12;
        *(float4*)&sps[l][q * 4] =
            *(const float4*)(sp + ((size_t)(b * LQ) + c * 32 + l) * 48 + q * 4);
    }
    float wd[16];
#pragma unroll
    for (int k = 0; k < 16; ++k) wd[k] = Wdt[k * DI + d];
    float bv = bdt[d];
    float Av[16];
    {
        const float4* ap = (const float4*)(Alog + (size_t)d * 16);
#pragma unroll
        for (int i = 0; i < 4; i++) {
            float4 v = ap[i];
            Av[4 * i + 0] = -expf(v.x);
            Av[4 * i + 1] = -expf(v.y);
            Av[4 * i + 2] = -expf(v.z);
            Av[4 * i + 3] = -expf(v.w);
        }
    }
    __syncthreads();
    float hst[16], P[16];
#pragma unroll
    for (int n = 0; n < 16; n++) { hst[n] = 0.f; P[n] = 1.f; }
    const float* up = hs + ((size_t)(b * LQ) + c * 32) * DI + d;
#pragma unroll 2
    for (int l = 0; l < 32; ++l) {
        float u = up[(size_t)l * DI];
        float4 t0 = *(const float4*)&sps[l][0];
        float4 t1 = *(const float4*)&sps[l][4];
        float4 t2 = *(const float4*)&sps[l][8];
        float4 t3 = *(const float4*)&sps[l][12];
        float acc = bv;
        acc = fmaf(t0.x, wd[0], acc);  acc = fmaf(t0.y, wd[1], acc);
        acc = fmaf(t0.z, wd[2], acc);  acc = fmaf(t0.w, wd[3], acc);
        acc = fmaf(t1.x, wd[4], acc);  acc = fmaf(t1.y, wd[5], acc);
        acc = fmaf(t1.z, wd[6], acc);  acc = fmaf(t1.w, wd[7], acc);
        acc = fmaf(t2.x, wd[8], acc);  acc = fmaf(t2.y, wd[9], acc);
        acc = fmaf(t2.z, wd[10], acc); acc = fmaf(t2.w, wd[11], acc);
        acc = fmaf(t3.x, wd[12], acc); acc = fmaf(t3.y, wd[13], acc);
        acc = fmaf(t3.z, wd[14], acc); acc = fmaf(t3.w, wd[15], acc);
        float delta = softplusf_(acc);
        float du = delta * u;
#pragma unroll
        for (int n = 0; n < 16; n++) {
            float dA = __expf(delta * Av[n]);
            hst[n] = fmaf(dA, hst[n], du * sps[l][16 + n]);
            P[n] *= dA;
        }
    }
    float* pb = PS + ((size_t)(b * 32 + c)) * (32 * DI) + d;
#pragma unroll
    for (int n = 0; n < 16; n++) {
        pb[(2 * n) * DI] = P[n];
        pb[(2 * n + 1) * DI] = hst[n];
    }
}

// ---------------- scan phase B
__global__ void k_scanB(float* __restrict__ PS) {
    int idx = blockIdx.x * 256 + threadIdx.x;
    int b = idx >> 13;
    int r = idx & 8191;
    float run = 0.f;
#pragma unroll 4
    for (int c = 0; c < 32; c++) {
        size_t oP = ((size_t)(b * 32 + c)) * (32 * DI) + ((r >> 9) * 2) * DI + (r & 511);
        float P = PS[oP];
        float hl = PS[oP + DI];
        PS[oP] = run;
        run = fmaf(P, run, hl);
    }
}

// ---------------- scan phase C
__global__ __launch_bounds__(256) void k_scanC(const float* __restrict__ hs,
                                               const float* __restrict__ sp,
                                               const float* __restrict__ xg,
                                               const float* __restrict__ PS,
                                               const float* __restrict__ Wdt,
                                               const float* __restrict__ bdt,
                                               const float* __restrict__ Alog,
                                               const float* __restrict__ Dsk,
                                               bf16* __restrict__ yh, bf16* __restrict__ yl) {
    int c = blockIdx.x, b = blockIdx.z;
    int t = threadIdx.x;
    int d = blockIdx.y * 256 + t;
    __shared__ float sps[32][48];
    for (int o = t; o < 32 * 12; o += 256) {
        int l = o / 12, q = o % 12;
        *(float4*)&sps[l][q * 4] =
            *(const float4*)(sp + ((size_t)(b * LQ) + c * 32 + l) * 48 + q * 4);
    }
    float wd[16];
#pragma unroll
    for (int k = 0; k < 16; ++k) wd[k] = Wdt[k * DI + d];
    float bv = bdt[d];
    float Av[16];
    {
        const float4* ap = (const float4*)(Alog + (size_t)d * 16);
#pragma unroll
        for (int i = 0; i < 4; i++) {
            float4 v = ap[i];
            Av[4 * i + 0] = -expf(v.x);
            Av[4 * i + 1] = -expf(v.y);
            Av[4 * i + 2] = -expf(v.z);
            Av[4 * i + 3] = -expf(v.w);
        }
    }
    float Dv = Dsk[d];
    float hst[16];
    {
        const float* pb = PS + ((size_t)(b * 32 + c)) * (32 * DI) + d;
#pragma unroll
        for (int n = 0; n < 16; n++) hst[n] = pb[(2 * n) * DI];
    }
    __syncthreads();
    const float* up = hs + ((size_t)(b * LQ) + c * 32) * DI + d;
    const float* gp = xg + ((size_t)(b * LQ) + c * 32) * 1024 + DI + d;
    bf16* yhp = yh + ((size_t)(b * LQ) + c * 32) * DI + d;
    bf16* ylp = yl + ((size_t)(b * LQ) + c * 32) * DI + d;
#pragma unroll 2
    for (int l = 0; l < 32; ++l) {
        float u = up[(size_t)l * DI];
        float gv = gp[(size_t)l * 1024];
        float4 t0 = *(const float4*)&sps[l][0];
        float4 t1 = *(const float4*)&sps[l][4];
        float4 t2 = *(const float4*)&sps[l][8];
        float4 t3 = *(const float4*)&sps[l][12];
        float acc = bv;
        acc = fmaf(t0.x, wd[0], acc);  acc = fmaf(t0.y, wd[1], acc);
        acc = fmaf(t0.z, wd[2], acc);  acc = fmaf(t0.w, wd[3], acc);
        acc = fmaf(t1.x, wd[4], acc);  acc = fmaf(t1.y, wd[5], acc);
        acc = fmaf(t1.z, wd[6], acc);  acc = fmaf(t1.w, wd[7], acc);
        acc = fmaf(t2.x, wd[8], acc);  acc = fmaf(t2.y, wd[9], acc);
        acc = fmaf(t2.z, wd[10], acc); acc = fmaf(t2.w, wd[11], acc);
        acc = fmaf(t3.x, wd[12], acc); acc = fmaf(t3.y, wd[13], acc);
        acc = fmaf(t3.z, wd[14], acc); acc = fmaf(t3.w, wd[15], acc);
        float delta = softplusf_(acc);
        float du = delta * u;
        float p = 0.f;
#pragma unroll
        for (int n = 0; n < 16; n++) {
            float dA = __expf(delta * Av[n]);
            hst[n] = fmaf(dA, hst[n], du * sps[l][16 + n]);
            p = fmaf(hst[n], sps[l][32 + n], p);
        }
        float yv = (p + u * Dv) * gv * sigmoidf_(gv);
        bf16 hb, lb;
        cvt_hilo(yv, hb, lb);
        yhp[(size_t)l * DI] = hb;
        ylp[(size_t)l * DI] = lb;
    }
}

// ---------------- head
__global__ __launch_bounds__(256) void k_head(const float* __restrict__ h,
                                              const float* __restrict__ Wa,
                                              const float* __restrict__ ba,
                                              const float* __restrict__ Wp,
                                              const float* __restrict__ bp,
                                              float* __restrict__ out) {
    int row = blockIdx.x * 4 + (threadIdx.x >> 6);
    int lane = threadIdx.x & 63;
    float4 v = ((const float4*)(h + (size_t)row * DM))[lane];
    float4 wa = ((const float4*)Wa)[lane];
    float4 wp = ((const float4*)Wp)[lane];
    float sa = v.x * wa.x + v.y * wa.y + v.z * wa.z + v.w * wa.w;
    float sph = v.x * wp.x + v.y * wp.y + v.z * wp.z + v.w * wp.w;
#pragma unroll
    for (int off = 32; off; off >>= 1) {
        sa += __shfl_xor(sa, off);
        sph += __shfl_xor(sph, off);
    }
    if (lane == 0) {
        out[(size_t)row * 2 + 0] = sa + ba[0];
        out[(size_t)row * 2 + 1] = tanhf(sph + bp[0]);
    }
}

extern "C" void kernel_launch(void* const* d_in, const int* in_sizes, int n_in,
                              void* d_out, int out_size, void* d_ws, size_t ws_size,
                              hipStream_t stream) {
    const float* x = (const float*)d_in[0];
    const float* pos = (const float*)d_in[1];
    const float* We = (const float*)d_in[2];
    const float* be = (const float*)d_in[3];
    const float* ln_w = (const float*)d_in[4];
    const float* W_in = (const float*)d_in[5];
    const float* conv_w = (const float*)d_in[6];
    const float* conv_b = (const float*)d_in[7];
    const float* W_x = (const float*)d_in[8];
    const float* W_dt = (const float*)d_in[9];
    const float* b_dt = (const float*)d_in[10];
    const float* A_log = (const float*)d_in[11];
    const float* D_skip = (const float*)d_in[12];
    const float* W_out = (const float*)d_in[13];
    const float* Wa = (const float*)d_in[14];
    const float* ba = (const float*)d_in[15];
    const float* Wp = (const float*)d_in[16];
    const float* bp = (const float*)d_in[17];

    float* ws = (float*)d_ws;
    float* h = ws;                        // 1,048,576 f
    float* xg = h + 1048576;              // 4,194,304 f
    float* hs = xg + 4194304;             // 2,097,152 f
    float* sp = hs + 2097152;             // 196,608 f
    float* PS = sp + 196608;              // 2,097,152 f
    bf16* y_hi = (bf16*)(PS + 2097152);   // 2,097,152 bf16
    bf16* y_lo = y_hi + 2097152;
    bf16* wtin = y_lo + 2097152;          // 2,097,152 bf16
    bf16* wtout = wtin + 2097152;         // 1,048,576 bf16

    k_wt1<<<dim3(8, 32, 8), 256, 0, stream>>>(W_in, wtin, 256, 1024);
    k_wt1<<<dim3(16, 8, 8), 256, 0, stream>>>(W_out, wtout, 512, 256);
    k_embed<<<4096, 256, 0, stream>>>(x, pos, We, be, h);
    for (int i = 0; i < NL; i++) {
        k_ln_gemm<<<dim3(16, 64), 256, 0, stream>>>(h, ln_w + i * DM,
                                                    wtin + (size_t)i * 1024 * 256, xg, sp);
        k_conv_sp<<<dim3(32, 8, 4), 256, 0, stream>>>(xg, conv_w + i * DI * KC,
                                                      conv_b + i * DI,
                                                      W_x + (size_t)i * DI * 48, hs, sp);
        k_scanA<<<dim3(32, 2, 4), 256, 0, stream>>>(hs, sp, W_dt + i * DTR * DI,
                                                    b_dt + i * DI, A_log + i * DI * NS, PS);
        k_scanB<<<128, 256, 0, stream>>>(PS);
        k_scanC<<<dim3(32, 2, 4), 256, 0, stream>>>(hs, sp, xg, PS, W_dt + i * DTR * DI,
                                                    b_dt + i * DI, A_log + i * DI * NS,
                                                    D_skip + i * DI, y_hi, y_lo);
        k_gemm2t<<<dim3(4, 64), 256, 0, stream>>>(y_hi, y_lo,
                                                  wtout + (size_t)i * 256 * 512, h,
                                                  4096, 256, 512);
    }
    k_head<<<1024, 256, 0, stream>>>(h, Wa, ba, Wp, bp, (float*)d_out);
}